// Round 1
// baseline (1020.970 us; speedup 1.0000x reference)
//
#include <hip/hip_runtime.h>
#include <math.h>

#define TOT_S   13294
#define NBATCH  2
#define CCH     512
#define MHEAD   8

#define BM 128
#define BN 128
#define BK 16
#define LDP 132   // padded LDS row stride (floats)

// ---------------------------------------------------------------------------
// GEMM 1: value[n,s,o] = sum_c Wv[o,c] * x[n,c,s] + bv[o], zeroed where mask.
// Output stored TRANSPOSED as (N, S, C) for coalesced channel reads later.
// ---------------------------------------------------------------------------
__global__ __launch_bounds__(256)
void gemm_value(const float* __restrict__ A,     // Wv (512,512) row-major
                const float* __restrict__ X,     // (N,512,S)
                const float* __restrict__ bias,  // (512)
                const unsigned char* __restrict__ mask, // (N,S)
                float* __restrict__ out)         // (N,S,512)
{
    __shared__ float As[BK][LDP];   // As[k][o]
    __shared__ float Bs[BK][LDP];   // Bs[k][s]
    const int n  = blockIdx.z;
    const int ob = blockIdx.y * BM;
    const int sb = blockIdx.x * BN;
    const int tid = threadIdx.x;
    const int ty = tid & 15;   // o octet (fastest -> o-contiguous stores)
    const int tx = tid >> 4;   // s octet
    const int a_row = tid >> 2;          // 0..63
    const int a_col = (tid & 3) << 2;    // k
    const int b_s   = (tid & 31) << 2;   // s within tile
    const int b_k   = tid >> 5;          // 0..7
    const float* Xn = X + (size_t)n * CCH * TOT_S;

    float acc[8][8];   // [s][o]
#pragma unroll
    for (int i = 0; i < 8; ++i)
#pragma unroll
        for (int j = 0; j < 8; ++j) acc[i][j] = 0.f;

    for (int k0 = 0; k0 < CCH; k0 += BK) {
#pragma unroll
        for (int r = 0; r < 2; ++r) {
            const int o = a_row + r * 64;
            const float4 v = *(const float4*)(A + (size_t)(ob + o) * CCH + k0 + a_col);
            As[a_col + 0][o] = v.x; As[a_col + 1][o] = v.y;
            As[a_col + 2][o] = v.z; As[a_col + 3][o] = v.w;
        }
#pragma unroll
        for (int r = 0; r < 2; ++r) {
            const int k = b_k + r * 8;
            const int s = sb + b_s;
            const float* p = Xn + (size_t)(k0 + k) * TOT_S + s;
            float4 v;
            if (s + 3 < TOT_S) v = *(const float4*)p;
            else {
                v.x = (s + 0 < TOT_S) ? p[0] : 0.f;
                v.y = (s + 1 < TOT_S) ? p[1] : 0.f;
                v.z = (s + 2 < TOT_S) ? p[2] : 0.f;
                v.w = 0.f;
            }
            *(float4*)&Bs[k][b_s] = v;
        }
        __syncthreads();
#pragma unroll
        for (int k = 0; k < BK; ++k) {
            float ra[8], rb[8];
            *(float4*)&ra[0] = *(const float4*)&As[k][ty * 8];
            *(float4*)&ra[4] = *(const float4*)&As[k][ty * 8 + 4];
            *(float4*)&rb[0] = *(const float4*)&Bs[k][tx * 8];
            *(float4*)&rb[4] = *(const float4*)&Bs[k][tx * 8 + 4];
#pragma unroll
            for (int i = 0; i < 8; ++i)
#pragma unroll
                for (int j = 0; j < 8; ++j)
                    acc[i][j] += rb[i] * ra[j];
        }
        __syncthreads();
    }

    float b8[8];
#pragma unroll
    for (int j = 0; j < 8; ++j) b8[j] = bias[ob + ty * 8 + j];
#pragma unroll
    for (int i = 0; i < 8; ++i) {
        const int s = sb + tx * 8 + i;
        if (s < TOT_S) {
            const float msk = mask[(size_t)n * TOT_S + s] ? 0.f : 1.f;
            float* op = out + ((size_t)n * TOT_S + s) * CCH + ob + ty * 8;
            float4 v0 = make_float4((acc[i][0] + b8[0]) * msk, (acc[i][1] + b8[1]) * msk,
                                    (acc[i][2] + b8[2]) * msk, (acc[i][3] + b8[3]) * msk);
            float4 v1 = make_float4((acc[i][4] + b8[4]) * msk, (acc[i][5] + b8[5]) * msk,
                                    (acc[i][6] + b8[6]) * msk, (acc[i][7] + b8[7]) * msk);
            *(float4*)op = v0; *(float4*)(op + 4) = v1;
        }
    }
}

// ---------------------------------------------------------------------------
// GEMM 2: offw[n,s,r] = sum_c Wcat[r,c] * xp[n,c,s] + bcat[r],  r in [0,96)
// Wcat = [Wloc (64 rows); Ww (32 rows)], xp = mask ? 0 : x + pos.
// ---------------------------------------------------------------------------
__global__ __launch_bounds__(256)
void gemm_offw(const float* __restrict__ Wloc, const float* __restrict__ bloc,
               const float* __restrict__ Ww,   const float* __restrict__ bw,
               const float* __restrict__ X,    const float* __restrict__ POS,
               const unsigned char* __restrict__ mask,
               float* __restrict__ out)        // (N,S,96)
{
    __shared__ float As[BK][LDP];
    __shared__ float Bs[BK][LDP];
    const int n  = blockIdx.z;
    const int sb = blockIdx.x * BN;
    const int tid = threadIdx.x;
    const int ty = tid & 15;
    const int tx = tid >> 4;
    const int a_row = tid >> 2;
    const int a_col = (tid & 3) << 2;
    const int b_s   = (tid & 31) << 2;
    const int b_k   = tid >> 5;
    const float* Xn = X   + (size_t)n * CCH * TOT_S;
    const float* Pn = POS + (size_t)n * CCH * TOT_S;

    float acc[8][8];
#pragma unroll
    for (int i = 0; i < 8; ++i)
#pragma unroll
        for (int j = 0; j < 8; ++j) acc[i][j] = 0.f;

    for (int k0 = 0; k0 < CCH; k0 += BK) {
#pragma unroll
        for (int r = 0; r < 2; ++r) {
            const int o = a_row + r * 64;
            if (o < 96) {
                const float* arow = (o < 64) ? (Wloc + (size_t)o * CCH)
                                             : (Ww + (size_t)(o - 64) * CCH);
                const float4 v = *(const float4*)(arow + k0 + a_col);
                As[a_col + 0][o] = v.x; As[a_col + 1][o] = v.y;
                As[a_col + 2][o] = v.z; As[a_col + 3][o] = v.w;
            }
        }
#pragma unroll
        for (int r = 0; r < 2; ++r) {
            const int k = b_k + r * 8;
            const int s = sb + b_s;
            const size_t off = (size_t)(k0 + k) * TOT_S + s;
            float4 v;
#pragma unroll
            for (int e = 0; e < 4; ++e) {
                float val = 0.f;
                if (s + e < TOT_S && !mask[(size_t)n * TOT_S + s + e])
                    val = Xn[off + e] + Pn[off + e];
                ((float*)&v)[e] = val;
            }
            *(float4*)&Bs[k][b_s] = v;
        }
        __syncthreads();
#pragma unroll
        for (int k = 0; k < BK; ++k) {
            float ra[8], rb[8];
            *(float4*)&ra[0] = *(const float4*)&As[k][ty * 8];
            *(float4*)&ra[4] = *(const float4*)&As[k][ty * 8 + 4];
            *(float4*)&rb[0] = *(const float4*)&Bs[k][tx * 8];
            *(float4*)&rb[4] = *(const float4*)&Bs[k][tx * 8 + 4];
#pragma unroll
            for (int i = 0; i < 8; ++i)
#pragma unroll
                for (int j = 0; j < 8; ++j)
                    acc[i][j] += rb[i] * ra[j];
        }
        __syncthreads();
    }

    if (ty < 12) {   // rows 0..95 only
        float b8[8];
#pragma unroll
        for (int j = 0; j < 8; ++j) {
            const int r = ty * 8 + j;
            b8[j] = (r < 64) ? bloc[r] : bw[r - 64];
        }
#pragma unroll
        for (int i = 0; i < 8; ++i) {
            const int s = sb + tx * 8 + i;
            if (s < TOT_S) {
                float* op = out + ((size_t)n * TOT_S + s) * 96 + ty * 8;
                float4 v0 = make_float4(acc[i][0] + b8[0], acc[i][1] + b8[1],
                                        acc[i][2] + b8[2], acc[i][3] + b8[3]);
                float4 v1 = make_float4(acc[i][4] + b8[4], acc[i][5] + b8[5],
                                        acc[i][6] + b8[6], acc[i][7] + b8[7]);
                *(float4*)op = v0; *(float4*)(op + 4) = v1;
            }
        }
    }
}

// ---------------------------------------------------------------------------
// Sampling: one wave per (n, m, s); lane = channel cm.
// samp[n,s,m*64+cm] = sum_f softmax_w[f] * bilinear_f(value[n, pix, m*64+cm])
// ---------------------------------------------------------------------------
__global__ __launch_bounds__(256)
void sample_attn(const float* __restrict__ value,   // (N,S,512)
                 const float* __restrict__ offw,    // (N,S,96)
                 const float* __restrict__ vsizes,  // (N,4,2) [w,h]
                 const float* __restrict__ vscales, // (N,4,2)
                 float* __restrict__ samp)          // (N,S,512)
{
    const int lane = threadIdx.x;                       // 0..63, channel
    const int item = blockIdx.x * blockDim.y + threadIdx.y;
    const int total = NBATCH * MHEAD * TOT_S;
    if (item >= total) return;
    const int s  = item % TOT_S;
    const int nm = item / TOT_S;
    const int m  = nm & 7;
    const int n  = nm >> 3;

    // query level + pixel-center coords (compile-time divisors per branch)
    int lvl; float prex, prey;
    if (s < 10000)      { lvl = 0; const int l = s;         const int q = l / 100; prey = q + 0.5f; prex = (l - q * 100) + 0.5f; }
    else if (s < 12500) { lvl = 1; const int l = s - 10000; const int q = l / 50;  prey = q + 0.5f; prex = (l - q * 50)  + 0.5f; }
    else if (s < 13125) { lvl = 2; const int l = s - 12500; const int q = l / 25;  prey = q + 0.5f; prex = (l - q * 25)  + 0.5f; }
    else                { lvl = 3; const int l = s - 13125; const int q = l / 13;  prey = q + 0.5f; prex = (l - q * 13)  + 0.5f; }

    const float* ow = offw + ((size_t)n * TOT_S + s) * 96;

    // softmax over the 4 attention logits
    const float w0 = ow[64 + m * 4 + 0], w1 = ow[64 + m * 4 + 1];
    const float w2 = ow[64 + m * 4 + 2], w3 = ow[64 + m * 4 + 3];
    const float mx = fmaxf(fmaxf(w0, w1), fmaxf(w2, w3));
    const float e0 = expf(w0 - mx), e1 = expf(w1 - mx), e2 = expf(w2 - mx), e3 = expf(w3 - mx);
    const float inv = 1.f / (e0 + e1 + e2 + e3);
    const float wgt[4] = { e0 * inv, e1 * inv, e2 * inv, e3 * inv };

    const int HS[4]  = { 100, 50, 25, 13 };
    const int WS[4]  = { 100, 50, 25, 13 };
    const int CUR[4] = { 0, 10000, 12500, 13125 };

    const float invsx = 1.f / vsizes[((n * 4) + lvl) * 2 + 0];
    const float invsy = 1.f / vsizes[((n * 4) + lvl) * 2 + 1];
    const float* vbase = value + (size_t)n * TOT_S * CCH + m * 64 + lane;

    float acc = 0.f;
#pragma unroll
    for (int f = 0; f < 4; ++f) {
        const float offx = ow[(m * 4 + f) * 2 + 0];
        const float offy = ow[(m * 4 + f) * 2 + 1];
        const float scx = 2.f * vscales[((n * 4) + f) * 2 + 0] * invsx;
        const float scy = 2.f * vscales[((n * 4) + f) * 2 + 1] * invsy;
        const float gx = (offx + prex) * scx - 1.f;
        const float gy = (offy + prey) * scy - 1.f;
        const int Wf = WS[f], Hf = HS[f], cf = CUR[f];
        const float xi = (gx + 1.f) * (Wf * 0.5f) - 0.5f;
        const float yi = (gy + 1.f) * (Hf * 0.5f) - 0.5f;
        const float x0f = floorf(xi), y0f = floorf(yi);
        const float wx1 = xi - x0f, wy1 = yi - y0f;
        const float wx0 = 1.f - wx1, wy0 = 1.f - wy1;
        const int x0 = (int)x0f, y0 = (int)y0f;
        const bool xin0 = (x0 >= 0) && (x0 < Wf);
        const bool xin1 = (x0 + 1 >= 0) && (x0 + 1 < Wf);
        const bool yin0 = (y0 >= 0) && (y0 < Hf);
        const bool yin1 = (y0 + 1 >= 0) && (y0 + 1 < Hf);
        float v00 = 0.f, v10 = 0.f, v01 = 0.f, v11 = 0.f;
        if (yin0) {
            const float* row = vbase + (size_t)(cf + y0 * Wf) * CCH;
            if (xin0) v00 = row[(size_t)x0 * CCH];
            if (xin1) v10 = row[(size_t)(x0 + 1) * CCH];
        }
        if (yin1) {
            const float* row = vbase + (size_t)(cf + (y0 + 1) * Wf) * CCH;
            if (xin0) v01 = row[(size_t)x0 * CCH];
            if (xin1) v11 = row[(size_t)(x0 + 1) * CCH];
        }
        acc += wgt[f] * (v00 * (wx0 * wy0) + v10 * (wx1 * wy0) +
                         v01 * (wx0 * wy1) + v11 * (wx1 * wy1));
    }
    samp[((size_t)n * TOT_S + s) * CCH + m * 64 + lane] = acc;
}

// ---------------------------------------------------------------------------
// GEMM 3: out[n,o,s] = (sum_c Wo[o,c] * samp[n,s,c] + bo[o]) * scale[o]
// B is K-contiguous (N,S,C); output (N,C,S).
// ---------------------------------------------------------------------------
__global__ __launch_bounds__(256)
void gemm_out(const float* __restrict__ A,      // Wo (512,512)
              const float* __restrict__ Bmat,   // samp (N,S,512)
              const float* __restrict__ bias, const float* __restrict__ scale,
              float* __restrict__ out)          // (N,512,S)
{
    __shared__ float As[BK][LDP];
    __shared__ float Bs[BK][LDP];
    const int n  = blockIdx.z;
    const int ob = blockIdx.y * BM;
    const int sb = blockIdx.x * BN;
    const int tid = threadIdx.x;
    const int tx = tid & 15;   // s octet (fastest -> s-contiguous stores)
    const int ty = tid >> 4;   // o octet
    const int a_row = tid >> 2;
    const int a_col = (tid & 3) << 2;
    const int b_sl  = tid >> 2;          // 0..63
    const int b_k4  = (tid & 3) << 2;    // 0,4,8,12

    float acc[8][8];   // [o][s]
#pragma unroll
    for (int i = 0; i < 8; ++i)
#pragma unroll
        for (int j = 0; j < 8; ++j) acc[i][j] = 0.f;

    for (int k0 = 0; k0 < CCH; k0 += BK) {
#pragma unroll
        for (int r = 0; r < 2; ++r) {
            const int o = a_row + r * 64;
            const float4 v = *(const float4*)(A + (size_t)(ob + o) * CCH + k0 + a_col);
            As[a_col + 0][o] = v.x; As[a_col + 1][o] = v.y;
            As[a_col + 2][o] = v.z; As[a_col + 3][o] = v.w;
        }
#pragma unroll
        for (int r = 0; r < 2; ++r) {
            const int sl = b_sl + r * 64;
            const int s  = sb + sl;
            float4 v = make_float4(0.f, 0.f, 0.f, 0.f);
            if (s < TOT_S)
                v = *(const float4*)(Bmat + ((size_t)n * TOT_S + s) * CCH + k0 + b_k4);
            Bs[b_k4 + 0][sl] = v.x; Bs[b_k4 + 1][sl] = v.y;
            Bs[b_k4 + 2][sl] = v.z; Bs[b_k4 + 3][sl] = v.w;
        }
        __syncthreads();
#pragma unroll
        for (int k = 0; k < BK; ++k) {
            float ra[8], rb[8];
            *(float4*)&ra[0] = *(const float4*)&As[k][ty * 8];
            *(float4*)&ra[4] = *(const float4*)&As[k][ty * 8 + 4];
            *(float4*)&rb[0] = *(const float4*)&Bs[k][tx * 8];
            *(float4*)&rb[4] = *(const float4*)&Bs[k][tx * 8 + 4];
#pragma unroll
            for (int j = 0; j < 8; ++j)
#pragma unroll
                for (int i = 0; i < 8; ++i)
                    acc[j][i] += ra[j] * rb[i];
        }
        __syncthreads();
    }

#pragma unroll
    for (int j = 0; j < 8; ++j) {
        const int o = ob + ty * 8 + j;
        const float bo_ = bias[o];
        const float sc_ = scale[o];
        float* op = out + ((size_t)n * CCH + o) * TOT_S + sb + tx * 8;
        const int sv = TOT_S - (sb + tx * 8);
        if (sv >= 8) {
            float4 v0 = make_float4((acc[j][0] + bo_) * sc_, (acc[j][1] + bo_) * sc_,
                                    (acc[j][2] + bo_) * sc_, (acc[j][3] + bo_) * sc_);
            float4 v1 = make_float4((acc[j][4] + bo_) * sc_, (acc[j][5] + bo_) * sc_,
                                    (acc[j][6] + bo_) * sc_, (acc[j][7] + bo_) * sc_);
            *(float4*)op = v0; *(float4*)(op + 4) = v1;
        } else {
            for (int i = 0; i < sv; ++i) op[i] = (acc[j][i] + bo_) * sc_;
        }
    }
}

// ---------------------------------------------------------------------------
extern "C" void kernel_launch(void* const* d_in, const int* in_sizes, int n_in,
                              void* d_out, int out_size, void* d_ws, size_t ws_size,
                              hipStream_t stream)
{
    const float* x     = (const float*)d_in[0];
    const float* pos   = (const float*)d_in[1];
    const unsigned char* mask = (const unsigned char*)d_in[2];
    const float* vsz   = (const float*)d_in[3];
    const float* vsc   = (const float*)d_in[4];
    const float* Wv    = (const float*)d_in[5];
    const float* bv    = (const float*)d_in[6];
    const float* Wloc  = (const float*)d_in[7];
    const float* bloc  = (const float*)d_in[8];
    const float* Ww    = (const float*)d_in[9];
    const float* bw    = (const float*)d_in[10];
    const float* Wo    = (const float*)d_in[11];
    const float* bo    = (const float*)d_in[12];
    const float* scale = (const float*)d_in[13];
    float* out = (float*)d_out;

    float* value = (float*)d_ws;                                   // N*S*512
    float* samp  = value + (size_t)NBATCH * TOT_S * CCH;           // N*S*512
    float* offw  = samp  + (size_t)NBATCH * TOT_S * CCH;           // N*S*96

    const int sTiles = (TOT_S + BN - 1) / BN;  // 104

    gemm_value<<<dim3(sTiles, CCH / BM, NBATCH), 256, 0, stream>>>(Wv, x, bv, mask, value);
    gemm_offw <<<dim3(sTiles, 1, NBATCH),        256, 0, stream>>>(Wloc, bloc, Ww, bw, x, pos, mask, offw);

    const int items = NBATCH * MHEAD * TOT_S;
    sample_attn<<<(items + 3) / 4, dim3(64, 4), 0, stream>>>(value, offw, vsz, vsc, samp);

    gemm_out<<<dim3(sTiles, CCH / BM, NBATCH), 256, 0, stream>>>(Wo, samp, bo, scale, out);
}

// Round 2
// 663.437 us; speedup vs baseline: 1.5389x; 1.5389x over previous
//
#include <hip/hip_runtime.h>
#include <math.h>

#define TOT_S   13294
#define NBATCH  2
#define CCH     512
#define MHEAD   8
#define PITCH   40   // LDS row pitch in bf16 elems (32 + 8 pad -> 80B, <=2-way bank alias)

typedef short     short8  __attribute__((ext_vector_type(8)));
typedef float     f32x4   __attribute__((ext_vector_type(4)));
typedef unsigned short u16x8 __attribute__((ext_vector_type(8)));
typedef unsigned short u16x4 __attribute__((ext_vector_type(4)));

__device__ __forceinline__ unsigned short f2bf(float f) {
    union { float f; unsigned int u; } v; v.f = f;
    unsigned int r = v.u + 0x7fffu + ((v.u >> 16) & 1u);   // RNE
    return (unsigned short)(r >> 16);
}
__device__ __forceinline__ float bf2f(unsigned short h) {
    union { unsigned int u; float f; } v; v.u = ((unsigned int)h) << 16;
    return v.f;
}

// ---------------------------------------------------------------------------
// Generic f32 -> bf16 cast (weights). n must be a multiple of 4.
// ---------------------------------------------------------------------------
__global__ void cast_f32_bf16(const float* __restrict__ src,
                              unsigned short* __restrict__ dst, int n4)
{
    const int i = blockIdx.x * blockDim.x + threadIdx.x;
    if (i < n4) {
        const float4 v = *(const float4*)(src + (size_t)i * 4);
        u16x4 o;
        o[0] = f2bf(v.x); o[1] = f2bf(v.y); o[2] = f2bf(v.z); o[3] = f2bf(v.w);
        *(u16x4*)(dst + (size_t)i * 4) = o;
    }
}

// ---------------------------------------------------------------------------
// Cast + transpose: xbt[n][s][c] = bf16(x[n][c][s]);
//                   xpbt[n][s][c] = mask ? 0 : bf16(x+pos).
// block (64,4): lane = s, ty = c-octet group. Coalesced strided column reads.
// ---------------------------------------------------------------------------
__global__ __launch_bounds__(256)
void cast_transpose(const float* __restrict__ x, const float* __restrict__ pos,
                    const unsigned char* __restrict__ mask,
                    unsigned short* __restrict__ xbt,
                    unsigned short* __restrict__ xpbt)
{
    const int lane = threadIdx.x;
    const int n = blockIdx.z;
    const int s = blockIdx.x * 64 + lane;
    if (s >= TOT_S) return;
    const int cb = (blockIdx.y * 4 + threadIdx.y) * 8;
    const float* xp = x   + ((size_t)n * CCH + cb) * TOT_S + s;
    const float* pp = pos + ((size_t)n * CCH + cb) * TOT_S + s;
    const bool mk = mask[(size_t)n * TOT_S + s] != 0;
    u16x8 vx, vp;
#pragma unroll
    for (int j = 0; j < 8; ++j) {
        const float a = xp[(size_t)j * TOT_S];
        const float b = pp[(size_t)j * TOT_S];
        vx[j] = f2bf(a);
        vp[j] = mk ? (unsigned short)0 : f2bf(a + b);
    }
    const size_t o = ((size_t)n * TOT_S + s) * CCH + cb;
    *(u16x8*)(xbt + o)  = vx;
    *(u16x8*)(xpbt + o) = vp;
}

// ---------------------------------------------------------------------------
// MFMA GEMM 1: value_b[n][s][o] = bf16( (sum_c Wv[o][c]*x[c][s] + bv[o]) * msk )
// A-operand = Wv rows (m = o), B-operand = xbt rows (n-dim = s).
// 128x128 tile, BK=32, 4 waves each 64x64 (4x4 grid of 16x16x32 mfma).
// ---------------------------------------------------------------------------
__global__ __launch_bounds__(256)
void gemm_value_mfma(const unsigned short* __restrict__ Wb,   // (512,512) bf16
                     const unsigned short* __restrict__ Act,  // xbt (N,S,512) bf16
                     const float* __restrict__ bv,
                     const unsigned char* __restrict__ mask,
                     unsigned short* __restrict__ valb)       // (N,S,512) bf16
{
    __shared__ unsigned short Wl[128 * PITCH];
    __shared__ unsigned short Al[128 * PITCH];
    const int n  = blockIdx.z;
    const int ob = blockIdx.y * 128;
    const int sb = blockIdx.x * 128;
    const int tid = threadIdx.x;
    const int r   = tid >> 1;
    const int seg = (tid & 1) * 16;
    const unsigned short* wsrc = Wb + ((size_t)(ob + r)) * CCH + seg;
    const int sr = min(sb + r, TOT_S - 1);
    const unsigned short* asrc = Act + ((size_t)n * TOT_S + sr) * CCH + seg;
    unsigned short* wdst = &Wl[r * PITCH + seg];
    unsigned short* adst = &Al[r * PITCH + seg];

    const int wave = tid >> 6, lane = tid & 63;
    const int m0 = (wave & 1) * 64, n0 = (wave >> 1) * 64;
    const int row16 = lane & 15, q = lane >> 4;

    f32x4 acc[4][4] = {};
    for (int k0 = 0; k0 < CCH; k0 += 32) {
        const u16x8 w0 = *(const u16x8*)(wsrc + k0);
        const u16x8 w1 = *(const u16x8*)(wsrc + k0 + 8);
        const u16x8 a0 = *(const u16x8*)(asrc + k0);
        const u16x8 a1 = *(const u16x8*)(asrc + k0 + 8);
        *(u16x8*)wdst = w0; *(u16x8*)(wdst + 8) = w1;
        *(u16x8*)adst = a0; *(u16x8*)(adst + 8) = a1;
        __syncthreads();
        short8 af[4], bfr[4];
#pragma unroll
        for (int mt = 0; mt < 4; ++mt)
            af[mt] = *(const short8*)&Wl[(m0 + mt * 16 + row16) * PITCH + q * 8];
#pragma unroll
        for (int nt = 0; nt < 4; ++nt)
            bfr[nt] = *(const short8*)&Al[(n0 + nt * 16 + row16) * PITCH + q * 8];
#pragma unroll
        for (int mt = 0; mt < 4; ++mt)
#pragma unroll
            for (int nt = 0; nt < 4; ++nt)
                acc[mt][nt] = __builtin_amdgcn_mfma_f32_16x16x32_bf16(
                    af[mt], bfr[nt], acc[mt][nt], 0, 0, 0);
        __syncthreads();
    }

#pragma unroll
    for (int nt = 0; nt < 4; ++nt) {
        const int s = sb + n0 + nt * 16 + row16;
        if (s >= TOT_S) continue;
        const float msk = mask[(size_t)n * TOT_S + s] ? 0.f : 1.f;
        unsigned short* orow = valb + ((size_t)n * TOT_S + s) * CCH + ob + m0;
#pragma unroll
        for (int mt = 0; mt < 4; ++mt) {
            const f32x4 bvv = *(const f32x4*)(bv + ob + m0 + mt * 16 + q * 4);
            const f32x4 a = acc[mt][nt];
            u16x4 ov;
            ov[0] = f2bf((a[0] + bvv[0]) * msk);
            ov[1] = f2bf((a[1] + bvv[1]) * msk);
            ov[2] = f2bf((a[2] + bvv[2]) * msk);
            ov[3] = f2bf((a[3] + bvv[3]) * msk);
            *(u16x4*)(orow + mt * 16 + q * 4) = ov;
        }
    }
}

// ---------------------------------------------------------------------------
// MFMA GEMM 2: offw[n][s][r] = sum_c Wcat[r][c]*xp[c][s] + bcat[r], r in [0,96)
// Wcat rows: 0..63 = Wloc, 64..95 = Ww, 96..127 zero-padded.
// ---------------------------------------------------------------------------
__global__ __launch_bounds__(256)
void gemm_offw_mfma(const unsigned short* __restrict__ Wlb,  // (64,512) bf16
                    const unsigned short* __restrict__ Wwb,  // (32,512) bf16
                    const float* __restrict__ bloc, const float* __restrict__ bw,
                    const unsigned short* __restrict__ Act,  // xpbt (N,S,512)
                    float* __restrict__ offw)                // (N,S,96)
{
    __shared__ unsigned short Wl[128 * PITCH];
    __shared__ unsigned short Al[128 * PITCH];
    const int n  = blockIdx.z;
    const int sb = blockIdx.x * 128;
    const int tid = threadIdx.x;
    const int r   = tid >> 1;
    const int seg = (tid & 1) * 16;
    const bool wzero = (r >= 96);
    const unsigned short* wsrc =
        (r < 64) ? (Wlb + (size_t)r * CCH + seg)
                 : (r < 96 ? (Wwb + (size_t)(r - 64) * CCH + seg)
                           : (Wlb + seg));
    const int sr = min(sb + r, TOT_S - 1);
    const unsigned short* asrc = Act + ((size_t)n * TOT_S + sr) * CCH + seg;
    unsigned short* wdst = &Wl[r * PITCH + seg];
    unsigned short* adst = &Al[r * PITCH + seg];

    const int wave = tid >> 6, lane = tid & 63;
    const int m0 = (wave & 1) * 64, n0 = (wave >> 1) * 64;
    const int row16 = lane & 15, q = lane >> 4;
    const int mtmax = (m0 == 0) ? 4 : 2;   // rows >= 96 unused

    f32x4 acc[4][4] = {};
    for (int k0 = 0; k0 < CCH; k0 += 32) {
        u16x8 w0 = {}, w1 = {};
        if (!wzero) { w0 = *(const u16x8*)(wsrc + k0); w1 = *(const u16x8*)(wsrc + k0 + 8); }
        const u16x8 a0 = *(const u16x8*)(asrc + k0);
        const u16x8 a1 = *(const u16x8*)(asrc + k0 + 8);
        *(u16x8*)wdst = w0; *(u16x8*)(wdst + 8) = w1;
        *(u16x8*)adst = a0; *(u16x8*)(adst + 8) = a1;
        __syncthreads();
        short8 af[4], bfr[4];
        for (int mt = 0; mt < mtmax; ++mt)
            af[mt] = *(const short8*)&Wl[(m0 + mt * 16 + row16) * PITCH + q * 8];
#pragma unroll
        for (int nt = 0; nt < 4; ++nt)
            bfr[nt] = *(const short8*)&Al[(n0 + nt * 16 + row16) * PITCH + q * 8];
        for (int mt = 0; mt < mtmax; ++mt)
#pragma unroll
            for (int nt = 0; nt < 4; ++nt)
                acc[mt][nt] = __builtin_amdgcn_mfma_f32_16x16x32_bf16(
                    af[mt], bfr[nt], acc[mt][nt], 0, 0, 0);
        __syncthreads();
    }

#pragma unroll
    for (int nt = 0; nt < 4; ++nt) {
        const int s = sb + n0 + nt * 16 + row16;
        if (s >= TOT_S) continue;
        float* orow = offw + ((size_t)n * TOT_S + s) * 96;
        for (int mt = 0; mt < mtmax; ++mt) {
            const int o = m0 + mt * 16 + q * 4;   // < 96 by construction
            const float* bsrc = (o < 64) ? (bloc + o) : (bw + o - 64);
            const f32x4 bb = *(const f32x4*)bsrc;
            f32x4 v = acc[mt][nt];
            v[0] += bb[0]; v[1] += bb[1]; v[2] += bb[2]; v[3] += bb[3];
            *(f32x4*)(orow + o) = v;
        }
    }
}

// ---------------------------------------------------------------------------
// Sampling: one wave per (n, m, s); lane = channel. bf16 value in, bf16 out.
// ---------------------------------------------------------------------------
__global__ __launch_bounds__(256)
void sample_attn(const unsigned short* __restrict__ value,  // (N,S,512) bf16
                 const float* __restrict__ offw,            // (N,S,96)
                 const float* __restrict__ vsizes,
                 const float* __restrict__ vscales,
                 unsigned short* __restrict__ samp)         // (N,S,512) bf16
{
    const int lane = threadIdx.x;
    const int item = blockIdx.x * blockDim.y + threadIdx.y;
    const int total = NBATCH * MHEAD * TOT_S;
    if (item >= total) return;
    const int s  = item % TOT_S;
    const int nm = item / TOT_S;
    const int m  = nm & 7;
    const int n  = nm >> 3;

    int lvl; float prex, prey;
    if (s < 10000)      { lvl = 0; const int l = s;         const int qq = l / 100; prey = qq + 0.5f; prex = (l - qq * 100) + 0.5f; }
    else if (s < 12500) { lvl = 1; const int l = s - 10000; const int qq = l / 50;  prey = qq + 0.5f; prex = (l - qq * 50)  + 0.5f; }
    else if (s < 13125) { lvl = 2; const int l = s - 12500; const int qq = l / 25;  prey = qq + 0.5f; prex = (l - qq * 25)  + 0.5f; }
    else                { lvl = 3; const int l = s - 13125; const int qq = l / 13;  prey = qq + 0.5f; prex = (l - qq * 13)  + 0.5f; }

    const float* ow = offw + ((size_t)n * TOT_S + s) * 96;

    const float w0 = ow[64 + m * 4 + 0], w1 = ow[64 + m * 4 + 1];
    const float w2 = ow[64 + m * 4 + 2], w3 = ow[64 + m * 4 + 3];
    const float mx = fmaxf(fmaxf(w0, w1), fmaxf(w2, w3));
    const float e0 = expf(w0 - mx), e1 = expf(w1 - mx), e2 = expf(w2 - mx), e3 = expf(w3 - mx);
    const float inv = 1.f / (e0 + e1 + e2 + e3);
    const float wgt[4] = { e0 * inv, e1 * inv, e2 * inv, e3 * inv };

    const int HS[4]  = { 100, 50, 25, 13 };
    const int WS[4]  = { 100, 50, 25, 13 };
    const int CUR[4] = { 0, 10000, 12500, 13125 };

    const float invsx = 1.f / vsizes[((n * 4) + lvl) * 2 + 0];
    const float invsy = 1.f / vsizes[((n * 4) + lvl) * 2 + 1];
    const unsigned short* vbase = value + (size_t)n * TOT_S * CCH + m * 64 + lane;

    float acc = 0.f;
#pragma unroll
    for (int f = 0; f < 4; ++f) {
        const float offx = ow[(m * 4 + f) * 2 + 0];
        const float offy = ow[(m * 4 + f) * 2 + 1];
        const float scx = 2.f * vscales[((n * 4) + f) * 2 + 0] * invsx;
        const float scy = 2.f * vscales[((n * 4) + f) * 2 + 1] * invsy;
        const float gx = (offx + prex) * scx - 1.f;
        const float gy = (offy + prey) * scy - 1.f;
        const int Wf = WS[f], Hf = HS[f], cf = CUR[f];
        const float xi = (gx + 1.f) * (Wf * 0.5f) - 0.5f;
        const float yi = (gy + 1.f) * (Hf * 0.5f) - 0.5f;
        const float x0f = floorf(xi), y0f = floorf(yi);
        const float wx1 = xi - x0f, wy1 = yi - y0f;
        const float wx0 = 1.f - wx1, wy0 = 1.f - wy1;
        const int x0 = (int)x0f, y0 = (int)y0f;
        const bool xin0 = (x0 >= 0) && (x0 < Wf);
        const bool xin1 = (x0 + 1 >= 0) && (x0 + 1 < Wf);
        const bool yin0 = (y0 >= 0) && (y0 < Hf);
        const bool yin1 = (y0 + 1 >= 0) && (y0 + 1 < Hf);
        float v00 = 0.f, v10 = 0.f, v01 = 0.f, v11 = 0.f;
        if (yin0) {
            const unsigned short* row = vbase + (size_t)(cf + y0 * Wf) * CCH;
            if (xin0) v00 = bf2f(row[(size_t)x0 * CCH]);
            if (xin1) v10 = bf2f(row[(size_t)(x0 + 1) * CCH]);
        }
        if (yin1) {
            const unsigned short* row = vbase + (size_t)(cf + (y0 + 1) * Wf) * CCH;
            if (xin0) v01 = bf2f(row[(size_t)x0 * CCH]);
            if (xin1) v11 = bf2f(row[(size_t)(x0 + 1) * CCH]);
        }
        acc += wgt[f] * (v00 * (wx0 * wy0) + v10 * (wx1 * wy0) +
                         v01 * (wx0 * wy1) + v11 * (wx1 * wy1));
    }
    samp[((size_t)n * TOT_S + s) * CCH + m * 64 + lane] = f2bf(acc);
}

// ---------------------------------------------------------------------------
// MFMA GEMM 3: out[n][o][s] = (sum_c Wo[o][c]*samp[s][c] + bo[o]) * scale[o]
// A-operand = samp rows (m = s), B-operand = Wo rows (n-dim = o)
// -> lane holds 4 consecutive s per frag: contiguous f32 stores to (N,C,S).
// ---------------------------------------------------------------------------
__global__ __launch_bounds__(256)
void gemm_out_mfma(const unsigned short* __restrict__ Wob,   // (512,512) bf16
                   const unsigned short* __restrict__ Sampb, // (N,S,512) bf16
                   const float* __restrict__ bo, const float* __restrict__ scale,
                   float* __restrict__ out)                  // (N,512,S)
{
    __shared__ unsigned short Sl[128 * PITCH];   // A-operand (samp rows)
    __shared__ unsigned short Wl[128 * PITCH];   // B-operand (Wo rows)
    const int n  = blockIdx.z;
    const int ob = blockIdx.y * 128;
    const int sb = blockIdx.x * 128;
    const int tid = threadIdx.x;
    const int r   = tid >> 1;
    const int seg = (tid & 1) * 16;
    const int sr = min(sb + r, TOT_S - 1);
    const unsigned short* ssrc = Sampb + ((size_t)n * TOT_S + sr) * CCH + seg;
    const unsigned short* wsrc = Wob + ((size_t)(ob + r)) * CCH + seg;
    unsigned short* sdst = &Sl[r * PITCH + seg];
    unsigned short* wdst = &Wl[r * PITCH + seg];

    const int wave = tid >> 6, lane = tid & 63;
    const int m0 = (wave & 1) * 64, n0 = (wave >> 1) * 64;
    const int row16 = lane & 15, q = lane >> 4;

    f32x4 acc[4][4] = {};
    for (int k0 = 0; k0 < CCH; k0 += 32) {
        const u16x8 s0v = *(const u16x8*)(ssrc + k0);
        const u16x8 s1v = *(const u16x8*)(ssrc + k0 + 8);
        const u16x8 w0v = *(const u16x8*)(wsrc + k0);
        const u16x8 w1v = *(const u16x8*)(wsrc + k0 + 8);
        *(u16x8*)sdst = s0v; *(u16x8*)(sdst + 8) = s1v;
        *(u16x8*)wdst = w0v; *(u16x8*)(wdst + 8) = w1v;
        __syncthreads();
        short8 af[4], bfr[4];
#pragma unroll
        for (int mt = 0; mt < 4; ++mt)
            af[mt] = *(const short8*)&Sl[(m0 + mt * 16 + row16) * PITCH + q * 8];
#pragma unroll
        for (int nt = 0; nt < 4; ++nt)
            bfr[nt] = *(const short8*)&Wl[(n0 + nt * 16 + row16) * PITCH + q * 8];
#pragma unroll
        for (int mt = 0; mt < 4; ++mt)
#pragma unroll
            for (int nt = 0; nt < 4; ++nt)
                acc[mt][nt] = __builtin_amdgcn_mfma_f32_16x16x32_bf16(
                    af[mt], bfr[nt], acc[mt][nt], 0, 0, 0);
        __syncthreads();
    }

#pragma unroll
    for (int nt = 0; nt < 4; ++nt) {
        const int o = ob + n0 + nt * 16 + row16;
        const float bo_ = bo[o];
        const float sc_ = scale[o];
        float* orow = out + ((size_t)n * CCH + o) * (size_t)TOT_S;
#pragma unroll
        for (int mt = 0; mt < 4; ++mt) {
            const int s0 = sb + m0 + mt * 16 + q * 4;
            const f32x4 a = acc[mt][nt];
            if (s0 + 3 < TOT_S) {
                float2 v0 = make_float2((a[0] + bo_) * sc_, (a[1] + bo_) * sc_);
                float2 v1 = make_float2((a[2] + bo_) * sc_, (a[3] + bo_) * sc_);
                *(float2*)(orow + s0) = v0;
                *(float2*)(orow + s0 + 2) = v1;
            } else {
                for (int i = 0; i < 4; ++i)
                    if (s0 + i < TOT_S) orow[s0 + i] = (a[i] + bo_) * sc_;
            }
        }
    }
}

// ---------------------------------------------------------------------------
extern "C" void kernel_launch(void* const* d_in, const int* in_sizes, int n_in,
                              void* d_out, int out_size, void* d_ws, size_t ws_size,
                              hipStream_t stream)
{
    const float* x     = (const float*)d_in[0];
    const float* pos   = (const float*)d_in[1];
    const unsigned char* mask = (const unsigned char*)d_in[2];
    const float* vsz   = (const float*)d_in[3];
    const float* vsc   = (const float*)d_in[4];
    const float* Wv    = (const float*)d_in[5];
    const float* bv    = (const float*)d_in[6];
    const float* Wloc  = (const float*)d_in[7];
    const float* bloc  = (const float*)d_in[8];
    const float* Ww    = (const float*)d_in[9];
    const float* bw    = (const float*)d_in[10];
    const float* Wo    = (const float*)d_in[11];
    const float* bo    = (const float*)d_in[12];
    const float* scale = (const float*)d_in[13];
    float* out = (float*)d_out;

    const size_t SC = (size_t)TOT_S * CCH;   // per-batch value elems
    unsigned short* valb  = (unsigned short*)d_ws;           // 2*SC bf16
    unsigned short* sampb = valb  + 2 * SC;                  // 2*SC
    unsigned short* xbt   = sampb + 2 * SC;                  // 2*SC
    unsigned short* xpbt  = xbt   + 2 * SC;                  // 2*SC
    float* offw = (float*)(xpbt + 2 * SC);                   // 2*S*96 f32
    unsigned short* wvb = (unsigned short*)(offw + 2 * (size_t)TOT_S * 96);
    unsigned short* wob = wvb + 512 * 512;
    unsigned short* wlb = wob + 512 * 512;
    unsigned short* wwb = wlb + 64 * 512;

    // weight casts
    cast_f32_bf16<<<256, 256, 0, stream>>>(Wv,   wvb, 512 * 512 / 4);
    cast_f32_bf16<<<256, 256, 0, stream>>>(Wo,   wob, 512 * 512 / 4);
    cast_f32_bf16<<<32,  256, 0, stream>>>(Wloc, wlb, 64 * 512 / 4);
    cast_f32_bf16<<<16,  256, 0, stream>>>(Ww,   wwb, 32 * 512 / 4);

    // x / x+pos transpose-cast to (N,S,C) bf16
    cast_transpose<<<dim3((TOT_S + 63) / 64, 16, NBATCH), dim3(64, 4), 0, stream>>>(
        x, pos, mask, xbt, xpbt);

    const int sTiles = (TOT_S + 127) / 128;  // 104

    gemm_value_mfma<<<dim3(sTiles, CCH / 128, NBATCH), 256, 0, stream>>>(
        wvb, xbt, bv, mask, valb);
    gemm_offw_mfma<<<dim3(sTiles, 1, NBATCH), 256, 0, stream>>>(
        wlb, wwb, bloc, bw, xpbt, offw);

    const int items = NBATCH * MHEAD * TOT_S;
    sample_attn<<<(items + 3) / 4, dim3(64, 4), 0, stream>>>(valb, offw, vsz, vsc, sampb);

    gemm_out_mfma<<<dim3(sTiles, CCH / 128, NBATCH), 256, 0, stream>>>(
        wob, sampb, bo, scale, out);
}

// Round 3
// 460.523 us; speedup vs baseline: 2.2170x; 1.4406x over previous
//
#include <hip/hip_runtime.h>
#include <math.h>

#define TOT_S   13294
#define NBATCH  2
#define CCH     512
#define MHEAD   8
#define PITCH   40   // LDS row pitch in bf16 elems (32 + 8 pad -> 80B)

typedef short     short8  __attribute__((ext_vector_type(8)));
typedef float     f32x4   __attribute__((ext_vector_type(4)));
typedef unsigned short u16x8 __attribute__((ext_vector_type(8)));
typedef unsigned short u16x4 __attribute__((ext_vector_type(4)));

__device__ __forceinline__ unsigned short f2bf(float f) {
    union { float f; unsigned int u; } v; v.f = f;
    unsigned int r = v.u + 0x7fffu + ((v.u >> 16) & 1u);   // RNE
    return (unsigned short)(r >> 16);
}
__device__ __forceinline__ float bf2f(unsigned short h) {
    union { unsigned int u; float f; } v; v.u = ((unsigned int)h) << 16;
    return v.f;
}

// ---------------------------------------------------------------------------
__global__ void cast_f32_bf16(const float* __restrict__ src,
                              unsigned short* __restrict__ dst, int n4)
{
    const int i = blockIdx.x * blockDim.x + threadIdx.x;
    if (i < n4) {
        const float4 v = *(const float4*)(src + (size_t)i * 4);
        u16x4 o;
        o[0] = f2bf(v.x); o[1] = f2bf(v.y); o[2] = f2bf(v.z); o[3] = f2bf(v.w);
        *(u16x4*)(dst + (size_t)i * 4) = o;
    }
}

// ---------------------------------------------------------------------------
__global__ __launch_bounds__(256)
void cast_transpose(const float* __restrict__ x, const float* __restrict__ pos,
                    const unsigned char* __restrict__ mask,
                    unsigned short* __restrict__ xbt,
                    unsigned short* __restrict__ xpbt)
{
    const int lane = threadIdx.x;
    const int n = blockIdx.z;
    const int s = blockIdx.x * 64 + lane;
    if (s >= TOT_S) return;
    const int cb = (blockIdx.y * 4 + threadIdx.y) * 8;
    const float* xp = x   + ((size_t)n * CCH + cb) * TOT_S + s;
    const float* pp = pos + ((size_t)n * CCH + cb) * TOT_S + s;
    const bool mk = mask[(size_t)n * TOT_S + s] != 0;
    u16x8 vx, vp;
#pragma unroll
    for (int j = 0; j < 8; ++j) {
        const float a = xp[(size_t)j * TOT_S];
        const float b = pp[(size_t)j * TOT_S];
        vx[j] = f2bf(a);
        vp[j] = mk ? (unsigned short)0 : f2bf(a + b);
    }
    const size_t o = ((size_t)n * TOT_S + s) * CCH + cb;
    *(u16x8*)(xbt + o)  = vx;
    *(u16x8*)(xpbt + o) = vp;
}

// ---------------------------------------------------------------------------
// MFMA GEMM 1: value_b[n][s][o] = bf16((sum_c Wv[o][c]*x[c][s] + bv[o])*msk)
// Register-prefetch pipelined K-loop (BK=32).
// ---------------------------------------------------------------------------
__global__ __launch_bounds__(256)
void gemm_value_mfma(const unsigned short* __restrict__ Wb,
                     const unsigned short* __restrict__ Act,
                     const float* __restrict__ bv,
                     const unsigned char* __restrict__ mask,
                     unsigned short* __restrict__ valb)
{
    __shared__ unsigned short Wl[128 * PITCH];
    __shared__ unsigned short Al[128 * PITCH];
    const int n  = blockIdx.z;
    const int ob = blockIdx.y * 128;
    const int sb = blockIdx.x * 128;
    const int tid = threadIdx.x;
    const int r   = tid >> 1;
    const int seg = (tid & 1) * 16;
    const unsigned short* wsrc = Wb + ((size_t)(ob + r)) * CCH + seg;
    const int sr = min(sb + r, TOT_S - 1);
    const unsigned short* asrc = Act + ((size_t)n * TOT_S + sr) * CCH + seg;
    unsigned short* wdst = &Wl[r * PITCH + seg];
    unsigned short* adst = &Al[r * PITCH + seg];

    const int wave = tid >> 6, lane = tid & 63;
    const int m0 = (wave & 1) * 64, n0 = (wave >> 1) * 64;
    const int row16 = lane & 15, q = lane >> 4;

    u16x8 w0 = *(const u16x8*)(wsrc);
    u16x8 w1 = *(const u16x8*)(wsrc + 8);
    u16x8 a0 = *(const u16x8*)(asrc);
    u16x8 a1 = *(const u16x8*)(asrc + 8);

    f32x4 acc[4][4] = {};
    for (int k0 = 0; k0 < CCH; k0 += 32) {
        *(u16x8*)wdst = w0; *(u16x8*)(wdst + 8) = w1;
        *(u16x8*)adst = a0; *(u16x8*)(adst + 8) = a1;
        __syncthreads();
        if (k0 + 32 < CCH) {
            w0 = *(const u16x8*)(wsrc + k0 + 32);
            w1 = *(const u16x8*)(wsrc + k0 + 40);
            a0 = *(const u16x8*)(asrc + k0 + 32);
            a1 = *(const u16x8*)(asrc + k0 + 40);
        }
        short8 af[4], bfr[4];
#pragma unroll
        for (int mt = 0; mt < 4; ++mt)
            af[mt] = *(const short8*)&Wl[(m0 + mt * 16 + row16) * PITCH + q * 8];
#pragma unroll
        for (int nt = 0; nt < 4; ++nt)
            bfr[nt] = *(const short8*)&Al[(n0 + nt * 16 + row16) * PITCH + q * 8];
#pragma unroll
        for (int mt = 0; mt < 4; ++mt)
#pragma unroll
            for (int nt = 0; nt < 4; ++nt)
                acc[mt][nt] = __builtin_amdgcn_mfma_f32_16x16x32_bf16(
                    af[mt], bfr[nt], acc[mt][nt], 0, 0, 0);
        __syncthreads();
    }

#pragma unroll
    for (int nt = 0; nt < 4; ++nt) {
        const int s = sb + n0 + nt * 16 + row16;
        if (s >= TOT_S) continue;
        const float msk = mask[(size_t)n * TOT_S + s] ? 0.f : 1.f;
        unsigned short* orow = valb + ((size_t)n * TOT_S + s) * CCH + ob + m0;
#pragma unroll
        for (int mt = 0; mt < 4; ++mt) {
            const f32x4 bvv = *(const f32x4*)(bv + ob + m0 + mt * 16 + q * 4);
            const f32x4 a = acc[mt][nt];
            u16x4 ov;
            ov[0] = f2bf((a[0] + bvv[0]) * msk);
            ov[1] = f2bf((a[1] + bvv[1]) * msk);
            ov[2] = f2bf((a[2] + bvv[2]) * msk);
            ov[3] = f2bf((a[3] + bvv[3]) * msk);
            *(u16x4*)(orow + mt * 16 + q * 4) = ov;
        }
    }
}

// ---------------------------------------------------------------------------
// MFMA GEMM 2 (offsets+logits). FULLY STATIC 4x4 unroll — no dynamic
// register indexing (round-2 scratch-spill bug). Rows 96..127 computed
// but never stored.
// ---------------------------------------------------------------------------
__global__ __launch_bounds__(256)
void gemm_offw_mfma(const unsigned short* __restrict__ Wlb,
                    const unsigned short* __restrict__ Wwb,
                    const float* __restrict__ bloc, const float* __restrict__ bw,
                    const unsigned short* __restrict__ Act,
                    float* __restrict__ offw)
{
    __shared__ unsigned short Wl[128 * PITCH];
    __shared__ unsigned short Al[128 * PITCH];
    const int n  = blockIdx.z;
    const int sb = blockIdx.x * 128;
    const int tid = threadIdx.x;
    const int r   = tid >> 1;
    const int seg = (tid & 1) * 16;
    const bool wzero = (r >= 96);
    const unsigned short* wsrc =
        (r < 64) ? (Wlb + (size_t)r * CCH + seg)
                 : (Wwb + (size_t)((r < 96 ? r : 95) - 64) * CCH + seg);
    const int sr = min(sb + r, TOT_S - 1);
    const unsigned short* asrc = Act + ((size_t)n * TOT_S + sr) * CCH + seg;
    unsigned short* wdst = &Wl[r * PITCH + seg];
    unsigned short* adst = &Al[r * PITCH + seg];

    const int wave = tid >> 6, lane = tid & 63;
    const int m0 = (wave & 1) * 64, n0 = (wave >> 1) * 64;
    const int row16 = lane & 15, q = lane >> 4;

    u16x8 w0 = {}, w1 = {};
    if (!wzero) { w0 = *(const u16x8*)(wsrc); w1 = *(const u16x8*)(wsrc + 8); }
    u16x8 a0 = *(const u16x8*)(asrc);
    u16x8 a1 = *(const u16x8*)(asrc + 8);

    f32x4 acc[4][4] = {};
    for (int k0 = 0; k0 < CCH; k0 += 32) {
        *(u16x8*)wdst = w0; *(u16x8*)(wdst + 8) = w1;
        *(u16x8*)adst = a0; *(u16x8*)(adst + 8) = a1;
        __syncthreads();
        if (k0 + 32 < CCH) {
            if (!wzero) {
                w0 = *(const u16x8*)(wsrc + k0 + 32);
                w1 = *(const u16x8*)(wsrc + k0 + 40);
            }
            a0 = *(const u16x8*)(asrc + k0 + 32);
            a1 = *(const u16x8*)(asrc + k0 + 40);
        }
        short8 af[4], bfr[4];
#pragma unroll
        for (int mt = 0; mt < 4; ++mt)
            af[mt] = *(const short8*)&Wl[(m0 + mt * 16 + row16) * PITCH + q * 8];
#pragma unroll
        for (int nt = 0; nt < 4; ++nt)
            bfr[nt] = *(const short8*)&Al[(n0 + nt * 16 + row16) * PITCH + q * 8];
#pragma unroll
        for (int mt = 0; mt < 4; ++mt)
#pragma unroll
            for (int nt = 0; nt < 4; ++nt)
                acc[mt][nt] = __builtin_amdgcn_mfma_f32_16x16x32_bf16(
                    af[mt], bfr[nt], acc[mt][nt], 0, 0, 0);
        __syncthreads();
    }

#pragma unroll
    for (int nt = 0; nt < 4; ++nt) {
        const int s = sb + n0 + nt * 16 + row16;
        if (s >= TOT_S) continue;
        float* orow = offw + ((size_t)n * TOT_S + s) * 96;
#pragma unroll
        for (int mt = 0; mt < 4; ++mt) {
            const int o = m0 + mt * 16 + q * 4;
            if (o < 96) {
                const float* bsrc = (o < 64) ? (bloc + o) : (bw + o - 64);
                const f32x4 bb = *(const f32x4*)bsrc;
                f32x4 v = acc[mt][nt];
                v[0] += bb[0]; v[1] += bb[1]; v[2] += bb[2]; v[3] += bb[3];
                *(f32x4*)(orow + o) = v;
            }
        }
    }
}

// ---------------------------------------------------------------------------
__global__ __launch_bounds__(256)
void sample_attn(const unsigned short* __restrict__ value,
                 const float* __restrict__ offw,
                 const float* __restrict__ vsizes,
                 const float* __restrict__ vscales,
                 unsigned short* __restrict__ samp)
{
    const int lane = threadIdx.x;
    const int item = blockIdx.x * blockDim.y + threadIdx.y;
    const int total = NBATCH * MHEAD * TOT_S;
    if (item >= total) return;
    const int s  = item % TOT_S;
    const int nm = item / TOT_S;
    const int m  = nm & 7;
    const int n  = nm >> 3;

    int lvl; float prex, prey;
    if (s < 10000)      { lvl = 0; const int l = s;         const int qq = l / 100; prey = qq + 0.5f; prex = (l - qq * 100) + 0.5f; }
    else if (s < 12500) { lvl = 1; const int l = s - 10000; const int qq = l / 50;  prey = qq + 0.5f; prex = (l - qq * 50)  + 0.5f; }
    else if (s < 13125) { lvl = 2; const int l = s - 12500; const int qq = l / 25;  prey = qq + 0.5f; prex = (l - qq * 25)  + 0.5f; }
    else                { lvl = 3; const int l = s - 13125; const int qq = l / 13;  prey = qq + 0.5f; prex = (l - qq * 13)  + 0.5f; }

    const float* ow = offw + ((size_t)n * TOT_S + s) * 96;

    const float w0 = ow[64 + m * 4 + 0], w1 = ow[64 + m * 4 + 1];
    const float w2 = ow[64 + m * 4 + 2], w3 = ow[64 + m * 4 + 3];
    const float mx = fmaxf(fmaxf(w0, w1), fmaxf(w2, w3));
    const float e0 = expf(w0 - mx), e1 = expf(w1 - mx), e2 = expf(w2 - mx), e3 = expf(w3 - mx);
    const float inv = 1.f / (e0 + e1 + e2 + e3);
    const float wgt[4] = { e0 * inv, e1 * inv, e2 * inv, e3 * inv };

    const int HS[4]  = { 100, 50, 25, 13 };
    const int WS[4]  = { 100, 50, 25, 13 };
    const int CUR[4] = { 0, 10000, 12500, 13125 };

    const float invsx = 1.f / vsizes[((n * 4) + lvl) * 2 + 0];
    const float invsy = 1.f / vsizes[((n * 4) + lvl) * 2 + 1];
    const unsigned short* vbase = value + (size_t)n * TOT_S * CCH + m * 64 + lane;

    float acc = 0.f;
#pragma unroll
    for (int f = 0; f < 4; ++f) {
        const float offx = ow[(m * 4 + f) * 2 + 0];
        const float offy = ow[(m * 4 + f) * 2 + 1];
        const float scx = 2.f * vscales[((n * 4) + f) * 2 + 0] * invsx;
        const float scy = 2.f * vscales[((n * 4) + f) * 2 + 1] * invsy;
        const float gx = (offx + prex) * scx - 1.f;
        const float gy = (offy + prey) * scy - 1.f;
        const int Wf = WS[f], Hf = HS[f], cf = CUR[f];
        const float xi = (gx + 1.f) * (Wf * 0.5f) - 0.5f;
        const float yi = (gy + 1.f) * (Hf * 0.5f) - 0.5f;
        const float x0f = floorf(xi), y0f = floorf(yi);
        const float wx1 = xi - x0f, wy1 = yi - y0f;
        const float wx0 = 1.f - wx1, wy0 = 1.f - wy1;
        const int x0 = (int)x0f, y0 = (int)y0f;
        const bool xin0 = (x0 >= 0) && (x0 < Wf);
        const bool xin1 = (x0 + 1 >= 0) && (x0 + 1 < Wf);
        const bool yin0 = (y0 >= 0) && (y0 < Hf);
        const bool yin1 = (y0 + 1 >= 0) && (y0 + 1 < Hf);
        float v00 = 0.f, v10 = 0.f, v01 = 0.f, v11 = 0.f;
        if (yin0) {
            const unsigned short* row = vbase + (size_t)(cf + y0 * Wf) * CCH;
            if (xin0) v00 = bf2f(row[(size_t)x0 * CCH]);
            if (xin1) v10 = bf2f(row[(size_t)(x0 + 1) * CCH]);
        }
        if (yin1) {
            const unsigned short* row = vbase + (size_t)(cf + (y0 + 1) * Wf) * CCH;
            if (xin0) v01 = bf2f(row[(size_t)x0 * CCH]);
            if (xin1) v11 = bf2f(row[(size_t)(x0 + 1) * CCH]);
        }
        acc += wgt[f] * (v00 * (wx0 * wy0) + v10 * (wx1 * wy0) +
                         v01 * (wx0 * wy1) + v11 * (wx1 * wy1));
    }
    samp[((size_t)n * TOT_S + s) * CCH + m * 64 + lane] = f2bf(acc);
}

// ---------------------------------------------------------------------------
// MFMA GEMM 3: out[n][o][s] = (sum_c Wo[o][c]*samp[s][c] + bo[o]) * scale[o]
// ---------------------------------------------------------------------------
__global__ __launch_bounds__(256)
void gemm_out_mfma(const unsigned short* __restrict__ Wob,
                   const unsigned short* __restrict__ Sampb,
                   const float* __restrict__ bo, const float* __restrict__ scale,
                   float* __restrict__ out)
{
    __shared__ unsigned short Sl[128 * PITCH];
    __shared__ unsigned short Wl[128 * PITCH];
    const int n  = blockIdx.z;
    const int ob = blockIdx.y * 128;
    const int sb = blockIdx.x * 128;
    const int tid = threadIdx.x;
    const int r   = tid >> 1;
    const int seg = (tid & 1) * 16;
    const int sr = min(sb + r, TOT_S - 1);
    const unsigned short* ssrc = Sampb + ((size_t)n * TOT_S + sr) * CCH + seg;
    const unsigned short* wsrc = Wob + ((size_t)(ob + r)) * CCH + seg;
    unsigned short* sdst = &Sl[r * PITCH + seg];
    unsigned short* wdst = &Wl[r * PITCH + seg];

    const int wave = tid >> 6, lane = tid & 63;
    const int m0 = (wave & 1) * 64, n0 = (wave >> 1) * 64;
    const int row16 = lane & 15, q = lane >> 4;

    u16x8 s0v = *(const u16x8*)(ssrc);
    u16x8 s1v = *(const u16x8*)(ssrc + 8);
    u16x8 w0v = *(const u16x8*)(wsrc);
    u16x8 w1v = *(const u16x8*)(wsrc + 8);

    f32x4 acc[4][4] = {};
    for (int k0 = 0; k0 < CCH; k0 += 32) {
        *(u16x8*)sdst = s0v; *(u16x8*)(sdst + 8) = s1v;
        *(u16x8*)wdst = w0v; *(u16x8*)(wdst + 8) = w1v;
        __syncthreads();
        if (k0 + 32 < CCH) {
            s0v = *(const u16x8*)(ssrc + k0 + 32);
            s1v = *(const u16x8*)(ssrc + k0 + 40);
            w0v = *(const u16x8*)(wsrc + k0 + 32);
            w1v = *(const u16x8*)(wsrc + k0 + 40);
        }
        short8 af[4], bfr[4];
#pragma unroll
        for (int mt = 0; mt < 4; ++mt)
            af[mt] = *(const short8*)&Sl[(m0 + mt * 16 + row16) * PITCH + q * 8];
#pragma unroll
        for (int nt = 0; nt < 4; ++nt)
            bfr[nt] = *(const short8*)&Wl[(n0 + nt * 16 + row16) * PITCH + q * 8];
#pragma unroll
        for (int mt = 0; mt < 4; ++mt)
#pragma unroll
            for (int nt = 0; nt < 4; ++nt)
                acc[mt][nt] = __builtin_amdgcn_mfma_f32_16x16x32_bf16(
                    af[mt], bfr[nt], acc[mt][nt], 0, 0, 0);
        __syncthreads();
    }

#pragma unroll
    for (int nt = 0; nt < 4; ++nt) {
        const int o = ob + n0 + nt * 16 + row16;
        const float bo_ = bo[o];
        const float sc_ = scale[o];
        float* orow = out + ((size_t)n * CCH + o) * (size_t)TOT_S;
#pragma unroll
        for (int mt = 0; mt < 4; ++mt) {
            const int s0 = sb + m0 + mt * 16 + q * 4;
            const f32x4 a = acc[mt][nt];
            if (s0 + 3 < TOT_S) {
                float2 v0 = make_float2((a[0] + bo_) * sc_, (a[1] + bo_) * sc_);
                float2 v1 = make_float2((a[2] + bo_) * sc_, (a[3] + bo_) * sc_);
                *(float2*)(orow + s0) = v0;
                *(float2*)(orow + s0 + 2) = v1;
            } else {
                for (int i = 0; i < 4; ++i)
                    if (s0 + i < TOT_S) orow[s0 + i] = (a[i] + bo_) * sc_;
            }
        }
    }
}

// ---------------------------------------------------------------------------
extern "C" void kernel_launch(void* const* d_in, const int* in_sizes, int n_in,
                              void* d_out, int out_size, void* d_ws, size_t ws_size,
                              hipStream_t stream)
{
    const float* x     = (const float*)d_in[0];
    const float* pos   = (const float*)d_in[1];
    const unsigned char* mask = (const unsigned char*)d_in[2];
    const float* vsz   = (const float*)d_in[3];
    const float* vsc   = (const float*)d_in[4];
    const float* Wv    = (const float*)d_in[5];
    const float* bv    = (const float*)d_in[6];
    const float* Wloc  = (const float*)d_in[7];
    const float* bloc  = (const float*)d_in[8];
    const float* Ww    = (const float*)d_in[9];
    const float* bw    = (const float*)d_in[10];
    const float* Wo    = (const float*)d_in[11];
    const float* bo    = (const float*)d_in[12];
    const float* scale = (const float*)d_in[13];
    float* out = (float*)d_out;

    const size_t SC = (size_t)TOT_S * CCH;
    unsigned short* valb  = (unsigned short*)d_ws;
    unsigned short* sampb = valb  + 2 * SC;
    unsigned short* xbt   = sampb + 2 * SC;
    unsigned short* xpbt  = xbt   + 2 * SC;
    float* offw = (float*)(xpbt + 2 * SC);
    unsigned short* wvb = (unsigned short*)(offw + 2 * (size_t)TOT_S * 96);
    unsigned short* wob = wvb + 512 * 512;
    unsigned short* wlb = wob + 512 * 512;
    unsigned short* wwb = wlb + 64 * 512;

    cast_f32_bf16<<<256, 256, 0, stream>>>(Wv,   wvb, 512 * 512 / 4);
    cast_f32_bf16<<<256, 256, 0, stream>>>(Wo,   wob, 512 * 512 / 4);
    cast_f32_bf16<<<32,  256, 0, stream>>>(Wloc, wlb, 64 * 512 / 4);
    cast_f32_bf16<<<16,  256, 0, stream>>>(Ww,   wwb, 32 * 512 / 4);

    cast_transpose<<<dim3((TOT_S + 63) / 64, 16, NBATCH), dim3(64, 4), 0, stream>>>(
        x, pos, mask, xbt, xpbt);

    const int sTiles = (TOT_S + 127) / 128;  // 104

    gemm_value_mfma<<<dim3(sTiles, CCH / 128, NBATCH), 256, 0, stream>>>(
        wvb, xbt, bv, mask, valb);
    gemm_offw_mfma<<<dim3(sTiles, 1, NBATCH), 256, 0, stream>>>(
        wlb, wwb, bloc, bw, xpbt, offw);

    const int items = NBATCH * MHEAD * TOT_S;
    sample_attn<<<(items + 3) / 4, dim3(64, 4), 0, stream>>>(valb, offw, vsz, vsc, sampb);

    gemm_out_mfma<<<dim3(sTiles, CCH / 128, NBATCH), 256, 0, stream>>>(
        wob, sampb, bo, scale, out);
}

// Round 4
// 314.241 us; speedup vs baseline: 3.2490x; 1.4655x over previous
//
#include <hip/hip_runtime.h>
#include <math.h>

#define TOT_S   13294
#define NBATCH  2
#define CCH     512
#define MHEAD   8
#define PITCH   40   // LDS row pitch in bf16 elems (32 + 8 pad -> 80B)

typedef short     short8  __attribute__((ext_vector_type(8)));
typedef float     f32x4   __attribute__((ext_vector_type(4)));
typedef unsigned short u16x8 __attribute__((ext_vector_type(8)));
typedef unsigned short u16x4 __attribute__((ext_vector_type(4)));

__device__ __forceinline__ unsigned short f2bf(float f) {
    union { float f; unsigned int u; } v; v.f = f;
    unsigned int r = v.u + 0x7fffu + ((v.u >> 16) & 1u);   // RNE
    return (unsigned short)(r >> 16);
}
__device__ __forceinline__ float bf2f(unsigned short h) {
    union { unsigned int u; float f; } v; v.u = ((unsigned int)h) << 16;
    return v.f;
}

// ---------------------------------------------------------------------------
__global__ void cast_f32_bf16(const float* __restrict__ src,
                              unsigned short* __restrict__ dst, int n4)
{
    const int i = blockIdx.x * blockDim.x + threadIdx.x;
    if (i < n4) {
        const float4 v = *(const float4*)(src + (size_t)i * 4);
        u16x4 o;
        o[0] = f2bf(v.x); o[1] = f2bf(v.y); o[2] = f2bf(v.z); o[3] = f2bf(v.w);
        *(u16x4*)(dst + (size_t)i * 4) = o;
    }
}

// ---------------------------------------------------------------------------
__global__ __launch_bounds__(256)
void cast_transpose(const float* __restrict__ x, const float* __restrict__ pos,
                    const unsigned char* __restrict__ mask,
                    unsigned short* __restrict__ xbt,
                    unsigned short* __restrict__ xpbt)
{
    const int lane = threadIdx.x;
    const int n = blockIdx.z;
    const int s = blockIdx.x * 64 + lane;
    if (s >= TOT_S) return;
    const int cb = (blockIdx.y * 4 + threadIdx.y) * 8;
    const float* xp = x   + ((size_t)n * CCH + cb) * TOT_S + s;
    const float* pp = pos + ((size_t)n * CCH + cb) * TOT_S + s;
    const bool mk = mask[(size_t)n * TOT_S + s] != 0;
    u16x8 vx, vp;
#pragma unroll
    for (int j = 0; j < 8; ++j) {
        const float a = xp[(size_t)j * TOT_S];
        const float b = pp[(size_t)j * TOT_S];
        vx[j] = f2bf(a);
        vp[j] = mk ? (unsigned short)0 : f2bf(a + b);
    }
    const size_t o = ((size_t)n * TOT_S + s) * CCH + cb;
    *(u16x8*)(xbt + o)  = vx;
    *(u16x8*)(xpbt + o) = vp;
}

// ---------------------------------------------------------------------------
// MFMA GEMM 1 (register-prefetch pipelined, BK=32)
// ---------------------------------------------------------------------------
__global__ __launch_bounds__(256)
void gemm_value_mfma(const unsigned short* __restrict__ Wb,
                     const unsigned short* __restrict__ Act,
                     const float* __restrict__ bv,
                     const unsigned char* __restrict__ mask,
                     unsigned short* __restrict__ valb)
{
    __shared__ unsigned short Wl[128 * PITCH];
    __shared__ unsigned short Al[128 * PITCH];
    const int n  = blockIdx.z;
    const int ob = blockIdx.y * 128;
    const int sb = blockIdx.x * 128;
    const int tid = threadIdx.x;
    const int r   = tid >> 1;
    const int seg = (tid & 1) * 16;
    const unsigned short* wsrc = Wb + ((size_t)(ob + r)) * CCH + seg;
    const int sr = min(sb + r, TOT_S - 1);
    const unsigned short* asrc = Act + ((size_t)n * TOT_S + sr) * CCH + seg;
    unsigned short* wdst = &Wl[r * PITCH + seg];
    unsigned short* adst = &Al[r * PITCH + seg];

    const int wave = tid >> 6, lane = tid & 63;
    const int m0 = (wave & 1) * 64, n0 = (wave >> 1) * 64;
    const int row16 = lane & 15, q = lane >> 4;

    u16x8 w0 = *(const u16x8*)(wsrc);
    u16x8 w1 = *(const u16x8*)(wsrc + 8);
    u16x8 a0 = *(const u16x8*)(asrc);
    u16x8 a1 = *(const u16x8*)(asrc + 8);

    f32x4 acc[4][4] = {};
    for (int k0 = 0; k0 < CCH; k0 += 32) {
        *(u16x8*)wdst = w0; *(u16x8*)(wdst + 8) = w1;
        *(u16x8*)adst = a0; *(u16x8*)(adst + 8) = a1;
        __syncthreads();
        if (k0 + 32 < CCH) {
            w0 = *(const u16x8*)(wsrc + k0 + 32);
            w1 = *(const u16x8*)(wsrc + k0 + 40);
            a0 = *(const u16x8*)(asrc + k0 + 32);
            a1 = *(const u16x8*)(asrc + k0 + 40);
        }
        short8 af[4], bfr[4];
#pragma unroll
        for (int mt = 0; mt < 4; ++mt)
            af[mt] = *(const short8*)&Wl[(m0 + mt * 16 + row16) * PITCH + q * 8];
#pragma unroll
        for (int nt = 0; nt < 4; ++nt)
            bfr[nt] = *(const short8*)&Al[(n0 + nt * 16 + row16) * PITCH + q * 8];
#pragma unroll
        for (int mt = 0; mt < 4; ++mt)
#pragma unroll
            for (int nt = 0; nt < 4; ++nt)
                acc[mt][nt] = __builtin_amdgcn_mfma_f32_16x16x32_bf16(
                    af[mt], bfr[nt], acc[mt][nt], 0, 0, 0);
        __syncthreads();
    }

#pragma unroll
    for (int nt = 0; nt < 4; ++nt) {
        const int s = sb + n0 + nt * 16 + row16;
        if (s >= TOT_S) continue;
        const float msk = mask[(size_t)n * TOT_S + s] ? 0.f : 1.f;
        unsigned short* orow = valb + ((size_t)n * TOT_S + s) * CCH + ob + m0;
#pragma unroll
        for (int mt = 0; mt < 4; ++mt) {
            const f32x4 bvv = *(const f32x4*)(bv + ob + m0 + mt * 16 + q * 4);
            const f32x4 a = acc[mt][nt];
            u16x4 ov;
            ov[0] = f2bf((a[0] + bvv[0]) * msk);
            ov[1] = f2bf((a[1] + bvv[1]) * msk);
            ov[2] = f2bf((a[2] + bvv[2]) * msk);
            ov[3] = f2bf((a[3] + bvv[3]) * msk);
            *(u16x4*)(orow + mt * 16 + q * 4) = ov;
        }
    }
}

// ---------------------------------------------------------------------------
// MFMA GEMM 2 (offsets+logits), fully static unroll.
// ---------------------------------------------------------------------------
__global__ __launch_bounds__(256)
void gemm_offw_mfma(const unsigned short* __restrict__ Wlb,
                    const unsigned short* __restrict__ Wwb,
                    const float* __restrict__ bloc, const float* __restrict__ bw,
                    const unsigned short* __restrict__ Act,
                    float* __restrict__ offw)
{
    __shared__ unsigned short Wl[128 * PITCH];
    __shared__ unsigned short Al[128 * PITCH];
    const int n  = blockIdx.z;
    const int sb = blockIdx.x * 128;
    const int tid = threadIdx.x;
    const int r   = tid >> 1;
    const int seg = (tid & 1) * 16;
    const bool wzero = (r >= 96);
    const unsigned short* wsrc =
        (r < 64) ? (Wlb + (size_t)r * CCH + seg)
                 : (Wwb + (size_t)((r < 96 ? r : 95) - 64) * CCH + seg);
    const int sr = min(sb + r, TOT_S - 1);
    const unsigned short* asrc = Act + ((size_t)n * TOT_S + sr) * CCH + seg;
    unsigned short* wdst = &Wl[r * PITCH + seg];
    unsigned short* adst = &Al[r * PITCH + seg];

    const int wave = tid >> 6, lane = tid & 63;
    const int m0 = (wave & 1) * 64, n0 = (wave >> 1) * 64;
    const int row16 = lane & 15, q = lane >> 4;

    u16x8 w0 = {}, w1 = {};
    if (!wzero) { w0 = *(const u16x8*)(wsrc); w1 = *(const u16x8*)(wsrc + 8); }
    u16x8 a0 = *(const u16x8*)(asrc);
    u16x8 a1 = *(const u16x8*)(asrc + 8);

    f32x4 acc[4][4] = {};
    for (int k0 = 0; k0 < CCH; k0 += 32) {
        *(u16x8*)wdst = w0; *(u16x8*)(wdst + 8) = w1;
        *(u16x8*)adst = a0; *(u16x8*)(adst + 8) = a1;
        __syncthreads();
        if (k0 + 32 < CCH) {
            if (!wzero) {
                w0 = *(const u16x8*)(wsrc + k0 + 32);
                w1 = *(const u16x8*)(wsrc + k0 + 40);
            }
            a0 = *(const u16x8*)(asrc + k0 + 32);
            a1 = *(const u16x8*)(asrc + k0 + 40);
        }
        short8 af[4], bfr[4];
#pragma unroll
        for (int mt = 0; mt < 4; ++mt)
            af[mt] = *(const short8*)&Wl[(m0 + mt * 16 + row16) * PITCH + q * 8];
#pragma unroll
        for (int nt = 0; nt < 4; ++nt)
            bfr[nt] = *(const short8*)&Al[(n0 + nt * 16 + row16) * PITCH + q * 8];
#pragma unroll
        for (int mt = 0; mt < 4; ++mt)
#pragma unroll
            for (int nt = 0; nt < 4; ++nt)
                acc[mt][nt] = __builtin_amdgcn_mfma_f32_16x16x32_bf16(
                    af[mt], bfr[nt], acc[mt][nt], 0, 0, 0);
        __syncthreads();
    }

#pragma unroll
    for (int nt = 0; nt < 4; ++nt) {
        const int s = sb + n0 + nt * 16 + row16;
        if (s >= TOT_S) continue;
        float* orow = offw + ((size_t)n * TOT_S + s) * 96;
#pragma unroll
        for (int mt = 0; mt < 4; ++mt) {
            const int o = m0 + mt * 16 + q * 4;
            if (o < 96) {
                const float* bsrc = (o < 64) ? (bloc + o) : (bw + o - 64);
                const f32x4 bb = *(const f32x4*)bsrc;
                f32x4 v = acc[mt][nt];
                v[0] += bb[0]; v[1] += bb[1]; v[2] += bb[2]; v[3] += bb[3];
                *(f32x4*)(orow + o) = v;
            }
        }
    }
}

// ---------------------------------------------------------------------------
// Sampling v2: ONE WAVE PER (n,s). lane -> head m = lane>>3, channels
// c = m*64 + (lane&7)*8 .. +8  (== lane*8: output row is one contiguous 1KiB
// store). 16B/lane gathers; branchless clamp + masked corner weights.
// ---------------------------------------------------------------------------
__global__ __launch_bounds__(256)
void sample_attn(const unsigned short* __restrict__ value,  // (N,S,512) bf16
                 const float* __restrict__ offw,            // (N,S,96)
                 const float* __restrict__ vsizes,
                 const float* __restrict__ vscales,
                 unsigned short* __restrict__ samp)         // (N,S,512) bf16
{
    const int lane = threadIdx.x;
    const int item = blockIdx.x * blockDim.y + threadIdx.y;
    const int total = NBATCH * TOT_S;
    if (item >= total) return;
    const int s = item % TOT_S;
    const int n = item / TOT_S;
    const int m = lane >> 3;

    // query level + pixel-center coords (wave-uniform)
    int lvl; float prex, prey;
    if (s < 10000)      { lvl = 0; const int l = s;         const int qq = l / 100; prey = qq + 0.5f; prex = (l - qq * 100) + 0.5f; }
    else if (s < 12500) { lvl = 1; const int l = s - 10000; const int qq = l / 50;  prey = qq + 0.5f; prex = (l - qq * 50)  + 0.5f; }
    else if (s < 13125) { lvl = 2; const int l = s - 12500; const int qq = l / 25;  prey = qq + 0.5f; prex = (l - qq * 25)  + 0.5f; }
    else                { lvl = 3; const int l = s - 13125; const int qq = l / 13;  prey = qq + 0.5f; prex = (l - qq * 13)  + 0.5f; }

    const float* ow = offw + ((size_t)n * TOT_S + s) * 96;

    // per-head softmax over 4 logits (replicated across the 8 lanes of a head)
    const float w0 = ow[64 + m * 4 + 0], w1 = ow[64 + m * 4 + 1];
    const float w2 = ow[64 + m * 4 + 2], w3 = ow[64 + m * 4 + 3];
    const float mx = fmaxf(fmaxf(w0, w1), fmaxf(w2, w3));
    const float e0 = expf(w0 - mx), e1 = expf(w1 - mx), e2 = expf(w2 - mx), e3 = expf(w3 - mx);
    const float inv = 1.f / (e0 + e1 + e2 + e3);
    const float wgt[4] = { e0 * inv, e1 * inv, e2 * inv, e3 * inv };

    const int HS[4]  = { 100, 50, 25, 13 };
    const int WS[4]  = { 100, 50, 25, 13 };
    const int CUR[4] = { 0, 10000, 12500, 13125 };

    const float invsx = 1.f / vsizes[((n * 4) + lvl) * 2 + 0];
    const float invsy = 1.f / vsizes[((n * 4) + lvl) * 2 + 1];
    // channel base: c = lane*8
    const unsigned short* vbase = value + (size_t)n * TOT_S * CCH + lane * 8;

    float acc[8] = {};
#pragma unroll
    for (int f = 0; f < 4; ++f) {
        const float offx = ow[(m * 4 + f) * 2 + 0];
        const float offy = ow[(m * 4 + f) * 2 + 1];
        const float scx = 2.f * vscales[((n * 4) + f) * 2 + 0] * invsx;
        const float scy = 2.f * vscales[((n * 4) + f) * 2 + 1] * invsy;
        const int Wf = WS[f], Hf = HS[f], cf = CUR[f];
        const float xi = (offx + prex) * scx * (Wf * 0.5f) - 0.5f;
        const float yi = (offy + prey) * scy * (Hf * 0.5f) - 0.5f;
        const float x0f = floorf(xi), y0f = floorf(yi);
        const float wx1 = xi - x0f, wy1 = yi - y0f;
        const float wx0 = 1.f - wx1, wy0 = 1.f - wy1;
        const int x0 = (int)x0f, y0 = (int)y0f;
        const bool xin0 = (x0 >= 0) && (x0 < Wf);
        const bool xin1 = (x0 + 1 >= 0) && (x0 + 1 < Wf);
        const bool yin0 = (y0 >= 0) && (y0 < Hf);
        const bool yin1 = (y0 + 1 >= 0) && (y0 + 1 < Hf);
        // masked corner weights (fold level weight in), clamped indices
        const float cw00 = (xin0 && yin0) ? wgt[f] * wx0 * wy0 : 0.f;
        const float cw10 = (xin1 && yin0) ? wgt[f] * wx1 * wy0 : 0.f;
        const float cw01 = (xin0 && yin1) ? wgt[f] * wx0 * wy1 : 0.f;
        const float cw11 = (xin1 && yin1) ? wgt[f] * wx1 * wy1 : 0.f;
        const int x0c = min(max(x0, 0), Wf - 1);
        const int x1c = min(max(x0 + 1, 0), Wf - 1);
        const int y0c = min(max(y0, 0), Hf - 1);
        const int y1c = min(max(y0 + 1, 0), Hf - 1);
        const unsigned short* row0 = vbase + (size_t)(cf + y0c * Wf) * CCH;
        const unsigned short* row1 = vbase + (size_t)(cf + y1c * Wf) * CCH;
        const u16x8 v00 = *(const u16x8*)(row0 + (size_t)x0c * CCH);
        const u16x8 v10 = *(const u16x8*)(row0 + (size_t)x1c * CCH);
        const u16x8 v01 = *(const u16x8*)(row1 + (size_t)x0c * CCH);
        const u16x8 v11 = *(const u16x8*)(row1 + (size_t)x1c * CCH);
#pragma unroll
        for (int j = 0; j < 8; ++j) {
            acc[j] += cw00 * bf2f(v00[j]) + cw10 * bf2f(v10[j])
                    + cw01 * bf2f(v01[j]) + cw11 * bf2f(v11[j]);
        }
    }

    u16x8 ov;
#pragma unroll
    for (int j = 0; j < 8; ++j) ov[j] = f2bf(acc[j]);
    *(u16x8*)(samp + ((size_t)n * TOT_S + s) * CCH + lane * 8) = ov;
}

// ---------------------------------------------------------------------------
// MFMA GEMM 3: out[n][o][s] = (sum_c Wo[o][c]*samp[s][c] + bo[o]) * scale[o]
// ---------------------------------------------------------------------------
__global__ __launch_bounds__(256)
void gemm_out_mfma(const unsigned short* __restrict__ Wob,
                   const unsigned short* __restrict__ Sampb,
                   const float* __restrict__ bo, const float* __restrict__ scale,
                   float* __restrict__ out)
{
    __shared__ unsigned short Sl[128 * PITCH];
    __shared__ unsigned short Wl[128 * PITCH];
    const int n  = blockIdx.z;
    const int ob = blockIdx.y * 128;
    const int sb = blockIdx.x * 128;
    const int tid = threadIdx.x;
    const int r   = tid >> 1;
    const int seg = (tid & 1) * 16;
    const int sr = min(sb + r, TOT_S - 1);
    const unsigned short* ssrc = Sampb + ((size_t)n * TOT_S + sr) * CCH + seg;
    const unsigned short* wsrc = Wob + ((size_t)(ob + r)) * CCH + seg;
    unsigned short* sdst = &Sl[r * PITCH + seg];
    unsigned short* wdst = &Wl[r * PITCH + seg];

    const int wave = tid >> 6, lane = tid & 63;
    const int m0 = (wave & 1) * 64, n0 = (wave >> 1) * 64;
    const int row16 = lane & 15, q = lane >> 4;

    u16x8 s0v = *(const u16x8*)(ssrc);
    u16x8 s1v = *(const u16x8*)(ssrc + 8);
    u16x8 w0v = *(const u16x8*)(wsrc);
    u16x8 w1v = *(const u16x8*)(wsrc + 8);

    f32x4 acc[4][4] = {};
    for (int k0 = 0; k0 < CCH; k0 += 32) {
        *(u16x8*)sdst = s0v; *(u16x8*)(sdst + 8) = s1v;
        *(u16x8*)wdst = w0v; *(u16x8*)(wdst + 8) = w1v;
        __syncthreads();
        if (k0 + 32 < CCH) {
            s0v = *(const u16x8*)(ssrc + k0 + 32);
            s1v = *(const u16x8*)(ssrc + k0 + 40);
            w0v = *(const u16x8*)(wsrc + k0 + 32);
            w1v = *(const u16x8*)(wsrc + k0 + 40);
        }
        short8 af[4], bfr[4];
#pragma unroll
        for (int mt = 0; mt < 4; ++mt)
            af[mt] = *(const short8*)&Sl[(m0 + mt * 16 + row16) * PITCH + q * 8];
#pragma unroll
        for (int nt = 0; nt < 4; ++nt)
            bfr[nt] = *(const short8*)&Wl[(n0 + nt * 16 + row16) * PITCH + q * 8];
#pragma unroll
        for (int mt = 0; mt < 4; ++mt)
#pragma unroll
            for (int nt = 0; nt < 4; ++nt)
                acc[mt][nt] = __builtin_amdgcn_mfma_f32_16x16x32_bf16(
                    af[mt], bfr[nt], acc[mt][nt], 0, 0, 0);
        __syncthreads();
    }

#pragma unroll
    for (int nt = 0; nt < 4; ++nt) {
        const int o = ob + n0 + nt * 16 + row16;
        const float bo_ = bo[o];
        const float sc_ = scale[o];
        float* orow = out + ((size_t)n * CCH + o) * (size_t)TOT_S;
#pragma unroll
        for (int mt = 0; mt < 4; ++mt) {
            const int s0 = sb + m0 + mt * 16 + q * 4;
            const f32x4 a = acc[mt][nt];
            if (s0 + 3 < TOT_S) {
                float2 v0 = make_float2((a[0] + bo_) * sc_, (a[1] + bo_) * sc_);
                float2 v1 = make_float2((a[2] + bo_) * sc_, (a[3] + bo_) * sc_);
                *(float2*)(orow + s0) = v0;
                *(float2*)(orow + s0 + 2) = v1;
            } else {
                for (int i = 0; i < 4; ++i)
                    if (s0 + i < TOT_S) orow[s0 + i] = (a[i] + bo_) * sc_;
            }
        }
    }
}

// ---------------------------------------------------------------------------
extern "C" void kernel_launch(void* const* d_in, const int* in_sizes, int n_in,
                              void* d_out, int out_size, void* d_ws, size_t ws_size,
                              hipStream_t stream)
{
    const float* x     = (const float*)d_in[0];
    const float* pos   = (const float*)d_in[1];
    const unsigned char* mask = (const unsigned char*)d_in[2];
    const float* vsz   = (const float*)d_in[3];
    const float* vsc   = (const float*)d_in[4];
    const float* Wv    = (const float*)d_in[5];
    const float* bv    = (const float*)d_in[6];
    const float* Wloc  = (const float*)d_in[7];
    const float* bloc  = (const float*)d_in[8];
    const float* Ww    = (const float*)d_in[9];
    const float* bw    = (const float*)d_in[10];
    const float* Wo    = (const float*)d_in[11];
    const float* bo    = (const float*)d_in[12];
    const float* scale = (const float*)d_in[13];
    float* out = (float*)d_out;

    const size_t SC = (size_t)TOT_S * CCH;
    unsigned short* valb  = (unsigned short*)d_ws;
    unsigned short* sampb = valb  + 2 * SC;
    unsigned short* xbt   = sampb + 2 * SC;
    unsigned short* xpbt  = xbt   + 2 * SC;
    float* offw = (float*)(xpbt + 2 * SC);
    unsigned short* wvb = (unsigned short*)(offw + 2 * (size_t)TOT_S * 96);
    unsigned short* wob = wvb + 512 * 512;
    unsigned short* wlb = wob + 512 * 512;
    unsigned short* wwb = wlb + 64 * 512;

    cast_f32_bf16<<<256, 256, 0, stream>>>(Wv,   wvb, 512 * 512 / 4);
    cast_f32_bf16<<<256, 256, 0, stream>>>(Wo,   wob, 512 * 512 / 4);
    cast_f32_bf16<<<32,  256, 0, stream>>>(Wloc, wlb, 64 * 512 / 4);
    cast_f32_bf16<<<16,  256, 0, stream>>>(Ww,   wwb, 32 * 512 / 4);

    cast_transpose<<<dim3((TOT_S + 63) / 64, 16, NBATCH), dim3(64, 4), 0, stream>>>(
        x, pos, mask, xbt, xpbt);

    const int sTiles = (TOT_S + 127) / 128;  // 104

    gemm_value_mfma<<<dim3(sTiles, CCH / 128, NBATCH), 256, 0, stream>>>(
        wvb, xbt, bv, mask, valb);
    gemm_offw_mfma<<<dim3(sTiles, 1, NBATCH), 256, 0, stream>>>(
        wlb, wwb, bloc, bw, xpbt, offw);

    const int items = NBATCH * TOT_S;   // one wave per (n,s) now
    sample_attn<<<(items + 3) / 4, dim3(64, 4), 0, stream>>>(valb, offw, vsz, vsc, sampb);

    gemm_out_mfma<<<dim3(sTiles, CCH / 128, NBATCH), 256, 0, stream>>>(
        wob, sampb, bo, scale, out);
}